// Round 3
// baseline (871.572 us; speedup 1.0000x reference)
//
#include <hip/hip_runtime.h>
#include <math.h>

#define NTH 256
#define LSEQ 2048
#define NF 4096
#define NH 512
#define NS 64
#define NB 8
#define NPAIR 256
#define TWO_PI 6.2831853071795864769f
#define PAD(i) ((i) + ((i) >> 4))

__device__ __forceinline__ float2 cmul(float2 a, float2 b) {
    return make_float2(a.x*b.x - a.y*b.y, a.x*b.y + a.y*b.x);
}
__device__ __forceinline__ float2 cmulw(float2 a, float wr, float wi) {
    return make_float2(a.x*wr - a.y*wi, a.x*wi + a.y*wr);
}

// ---- 16-point DIF DFT in registers. Output: Y[k] = y[rev4[k]]. ----
// Forward uses e^{-i}, INV conjugates all twiddles.
template<bool INV>
__device__ __forceinline__ void fft16(float2* y) {
    const float sg = INV ? -1.f : 1.f;
    const float WR[8] = {1.f, 0.9238795325112867f, 0.7071067811865476f,
                         0.3826834323650898f, 0.f, -0.3826834323650898f,
                         -0.7071067811865476f, -0.9238795325112867f};
    const float WI[8] = {0.f, -0.3826834323650898f, -0.7071067811865476f,
                         -0.9238795325112867f, -1.f, -0.9238795325112867f,
                         -0.7071067811865476f, -0.3826834323650898f};
    #pragma unroll
    for (int j = 0; j < 8; ++j) {
        float2 a = y[j], b = y[j+8];
        float2 d = make_float2(a.x-b.x, a.y-b.y);
        y[j] = make_float2(a.x+b.x, a.y+b.y);
        y[j+8] = cmulw(d, WR[j], sg*WI[j]);
    }
    #pragma unroll
    for (int h = 0; h < 16; h += 8)
        #pragma unroll
        for (int j = 0; j < 4; ++j) {
            float2 a = y[h+j], b = y[h+j+4];
            float2 d = make_float2(a.x-b.x, a.y-b.y);
            y[h+j] = make_float2(a.x+b.x, a.y+b.y);
            y[h+j+4] = cmulw(d, WR[2*j], sg*WI[2*j]);
        }
    #pragma unroll
    for (int h = 0; h < 16; h += 4)
        #pragma unroll
        for (int j = 0; j < 2; ++j) {
            float2 a = y[h+j], b = y[h+j+2];
            float2 d = make_float2(a.x-b.x, a.y-b.y);
            y[h+j] = make_float2(a.x+b.x, a.y+b.y);
            y[h+j+2] = (j == 0) ? d : make_float2(sg*d.y, -sg*d.x);
        }
    #pragma unroll
    for (int h = 0; h < 16; h += 2) {
        float2 a = y[h], b = y[h+1];
        y[h] = make_float2(a.x+b.x, a.y+b.y);
        y[h+1] = make_float2(a.x-b.x, a.y-b.y);
    }
}

// ---- 8-point DIF DFT in registers. Output: Y[k] = y[rev3[k]]. ----
template<bool INV>
__device__ __forceinline__ void fft8(float2* y) {
    const float sg = INV ? -1.f : 1.f;
    const float RH = 0.7071067811865476f;
    const float WR[4] = {1.f, RH, 0.f, -RH};
    const float WI[4] = {0.f, -RH, -1.f, -RH};
    #pragma unroll
    for (int j = 0; j < 4; ++j) {
        float2 a = y[j], b = y[j+4];
        float2 d = make_float2(a.x-b.x, a.y-b.y);
        y[j] = make_float2(a.x+b.x, a.y+b.y);
        y[j+4] = cmulw(d, WR[j], sg*WI[j]);
    }
    #pragma unroll
    for (int h = 0; h < 8; h += 4)
        #pragma unroll
        for (int j = 0; j < 2; ++j) {
            float2 a = y[h+j], b = y[h+j+2];
            float2 d = make_float2(a.x-b.x, a.y-b.y);
            y[h+j] = make_float2(a.x+b.x, a.y+b.y);
            y[h+j+2] = (j == 0) ? d : make_float2(sg*d.y, -sg*d.x);
        }
    #pragma unroll
    for (int h = 0; h < 8; h += 2) {
        float2 a = y[h], b = y[h+1];
        y[h] = make_float2(a.x+b.x, a.y+b.y);
        y[h+1] = make_float2(a.x-b.x, a.y-b.y);
    }
}

// One radix-16 Cooley-Tukey pass on padded LDS. Forward (DIF):
//   out[base+k*str] = DFT16(in[base+j*str])[k] * e^{-2pi i r k / M}, ang1 = -2pi r/M
// Inverse (DIT, transpose): pre-twiddle with ang1 = +2pi r/M, inverse DFT16.
template<bool INV>
__device__ __forceinline__ void pass16(float2* s, int base, int str, float ang1) {
    const int rev4[16] = {0,8,4,12,2,10,6,14,1,9,5,13,3,11,7,15};
    float2 y[16];
    float sn, cs;
    __sincosf(ang1, &sn, &cs);
    float2 wb = make_float2(cs, sn);
    if (!INV) {
        #pragma unroll
        for (int j = 0; j < 16; ++j) y[j] = s[PAD(base + j*str)];
        fft16<false>(y);
        float2 w = make_float2(1.f, 0.f);
        s[PAD(base)] = y[0];
        #pragma unroll
        for (int k = 1; k < 16; ++k) {
            w = cmul(w, wb);
            s[PAD(base + k*str)] = cmul(y[rev4[k]], w);
        }
    } else {
        float2 w = make_float2(1.f, 0.f);
        y[0] = s[PAD(base)];
        #pragma unroll
        for (int k = 1; k < 16; ++k) {
            w = cmul(w, wb);
            y[k] = cmul(s[PAD(base + k*str)], w);
        }
        fft16<true>(y);
        #pragma unroll
        for (int j = 0; j < 16; ++j) s[PAD(base + j*str)] = y[rev4[j]];
    }
}

template<bool INV>
__device__ __forceinline__ void pass8(float2* s, int base, int str, float ang1) {
    const int rev3[8] = {0,4,2,6,1,5,3,7};
    float2 y[8];
    float sn, cs;
    __sincosf(ang1, &sn, &cs);
    float2 wb = make_float2(cs, sn);
    if (!INV) {
        #pragma unroll
        for (int j = 0; j < 8; ++j) y[j] = s[PAD(base + j*str)];
        fft8<false>(y);
        float2 w = make_float2(1.f, 0.f);
        s[PAD(base)] = y[0];
        #pragma unroll
        for (int k = 1; k < 8; ++k) {
            w = cmul(w, wb);
            s[PAD(base + k*str)] = cmul(y[rev3[k]], w);
        }
    } else {
        float2 w = make_float2(1.f, 0.f);
        y[0] = s[PAD(base)];
        #pragma unroll
        for (int k = 1; k < 8; ++k) {
            w = cmul(w, wb);
            y[k] = cmul(s[PAD(base + k*str)], w);
        }
        fft8<true>(y);
        #pragma unroll
        for (int j = 0; j < 8; ++j) s[PAD(base + j*str)] = y[rev3[j]];
    }
}

__device__ __forceinline__ float2 finalize_ar(const float* s, float tg) {
    float denx = 1.0f + s[6], deny = s[7];
    float dinv = 1.0f / (denx*denx + deny*deny);
    float numx = s[2]*s[4] - s[3]*s[5];
    float numy = s[2]*s[5] + s[3]*s[4];
    float qx = (numx*denx + numy*deny) * dinv;
    float qy = (numy*denx - numx*deny) * dinv;
    float kx = s[0] - qx, ky = s[1] - qy;
    return make_float2(kx - tg*ky, ky + tg*kx);   // (1 + i*tg) * k
}

// Cauchy evaluation; writes symmetrized A (dr11-permuted) and even Kf bins
// (dr12-permuted). Coefficients lane-resident, broadcast via __shfl.
__global__ __launch_bounds__(NTH) void k_cauchy(
    const float* __restrict__ Lre, const float* __restrict__ Lim,
    const float* __restrict__ Pm, const float* __restrict__ Bm,
    const float* __restrict__ Cm, const float* __restrict__ Dp,
    const float* __restrict__ logstep,
    float2* __restrict__ Aperm, float2* __restrict__ KfP)
{
    const int h = blockIdx.x >> 1;
    const int q = blockIdx.x & 1;
    const int tid = threadIdx.x;
    const int lane = tid & 63;
    const int i = h * NS + lane;
    const float Lx = fminf(Lre[i], -1e-4f), Ly = Lim[i];
    const float Px = Pm[2*i], Py = Pm[2*i+1];
    const float Bx = Bm[2*i], By = Bm[2*i+1];
    const float Cx = Cm[2*i], Cy = Cm[2*i+1];
    const float c00x = Cx*Bx + Cy*By, c00y = Cx*By - Cy*Bx;  // conj(C)*B
    const float c01x = Cx*Px + Cy*Py, c01y = Cx*Py - Cy*Px;  // conj(C)*P
    const float c10x = Px*Bx + Py*By, c10y = Px*By - Py*Bx;  // conj(P)*B
    const float c11x = Px*Px + Py*Py;                        // conj(P)*P real
    float t00x = c00x, t00y = c00y;
    #pragma unroll
    for (int off = 32; off; off >>= 1) {
        t00x += __shfl_xor(t00x, off);
        t00y += __shfl_xor(t00y, off);
    }
    const float step = expf(logstep[h]);
    const float a2s = 2.0f / step;
    const float dD = Dp[h];
    const float s4 = 1.0f / (float)NF;
    float2* Ah = Aperm + (size_t)h * LSEQ;
    float2* Kh = KfP + (size_t)h * NF;
    const int cnt = 512 + q;
    for (int ii = tid; ii < cnt; ii += NTH) {
        const int l = q * 512 + ii;          // e in [0, 1024]
        const int lp = LSEQ - l;             // partner l in [1024, 2048]
        float r1 = (float)l * (1.0f / (float)LSEQ);
        float r2 = (float)lp * (1.0f / (float)LSEQ);
        float tg1 = sinpif(r1) / cospif(r1);
        float tg2 = sinpif(r2) / cospif(r2);
        float g1 = a2s * tg1, g2 = a2s * tg2;
        float sa[8] = {0,0,0,0,0,0,0,0};
        float sb[8] = {0,0,0,0,0,0,0,0};
        #pragma unroll
        for (int n = 0; n < NS; ++n) {
            float lx = __shfl(Lx, n), ly = __shfl(Ly, n);
            float a0x = __shfl(c00x, n), a0y = __shfl(c00y, n);
            float a1x = __shfl(c01x, n), a1y = __shfl(c01y, n);
            float a2x = __shfl(c10x, n), a2y = __shfl(c10y, n);
            float a3x = __shfl(c11x, n);
            float dre = -lx;
            float di1 = g1 - ly, di2 = g2 - ly;
            float iv1 = 1.0f / (dre*dre + di1*di1);
            float iv2 = 1.0f / (dre*dre + di2*di2);
            float rx1 = dre*iv1, ry1 = -di1*iv1;
            float rx2 = dre*iv2, ry2 = -di2*iv2;
            sa[0] += a0x*rx1 - a0y*ry1; sa[1] += a0x*ry1 + a0y*rx1;
            sa[2] += a1x*rx1 - a1y*ry1; sa[3] += a1x*ry1 + a1y*rx1;
            sa[4] += a2x*rx1 - a2y*ry1; sa[5] += a2x*ry1 + a2y*rx1;
            sa[6] += a3x*rx1;           sa[7] += a3x*ry1;
            sb[0] += a0x*rx2 - a0y*ry2; sb[1] += a0x*ry2 + a0y*rx2;
            sb[2] += a1x*rx2 - a1y*ry2; sb[3] += a1x*ry2 + a1y*rx2;
            sb[4] += a2x*rx2 - a2y*ry2; sb[5] += a2x*ry2 + a2y*rx2;
            sb[6] += a3x*rx2;           sb[7] += a3x*ry2;
        }
        float2 ar1 = finalize_ar(sa, tg1);
        float2 ar2 = finalize_ar(sb, tg2);
        if (l == 1024) {  // tan -> inf limit: c_scale*k -> (step/2)*sum(ab00)
            ar1 = make_float2(0.5f*step*t00x, 0.5f*step*t00y);
            ar2 = ar1;
        }
        // A[l] = (at[l] + conj(at[2048-l]))/2 ; A[2048-l] = conj(A[l])
        float2 A = make_float2(0.5f*(ar1.x + ar2.x), 0.5f*(ar1.y - ar2.y));
        const int l2 = lp & (LSEQ - 1);
        Ah[((l&15)<<7) | (((l>>4)&15)<<3) | (l>>8)] = A;
        int k1 = (2*l) & (NF - 1);
        Kh[((k1&15)<<8) | (k1&240) | (k1>>8)] =
            make_float2((A.x + dD)*s4, A.y*s4);
        if (l2 != l) {
            Ah[((l2&15)<<7) | (((l2>>4)&15)<<3) | (l2>>8)] =
                make_float2(A.x, -A.y);
            int k2 = (2*l2) & (NF - 1);
            Kh[((k2&15)<<8) | (k2&240) | (k2>>8)] =
                make_float2((A.x + dD)*s4, -A.y*s4);
        }
    }
}

// Odd Kf bins: IDFT2048(A) -> K ; modulate e^{-2pi i t/4096}; DFT2048 -> odd.
// Two heads per block (128 threads each). 2048 = 16*16*8 mixed radix.
__global__ __launch_bounds__(NTH) void k_kspec(
    const float2* __restrict__ Aperm, const float* __restrict__ Dp,
    float2* __restrict__ KfP)
{
    __shared__ float2 sh[2 * 2176];
    const int hh = blockIdx.x * 2 + (threadIdx.x >> 7);
    const int t7 = threadIdx.x & 127;
    float2* sb = sh + (threadIdx.x >> 7) * 2176;
    const float2* Ah = Aperm + (size_t)hh * LSEQ;
    for (int p = t7; p < LSEQ; p += 128) sb[PAD(p)] = Ah[p];
    __syncthreads();
    // ---- inverse DIT 2048 (input dr11-permuted -> natural time) ----
    pass8<true>(sb, t7 << 3, 1, 0.f);
    pass8<true>(sb, (t7 + 128) << 3, 1, 0.f);
    __syncthreads();
    pass16<true>(sb, ((t7 >> 3) << 7) | (t7 & 7), 8,
                 TWO_PI * (float)(t7 & 7) / 128.f);
    __syncthreads();
    pass16<true>(sb, t7, 128, TWO_PI * (float)t7 / 2048.f);
    __syncthreads();
    // ---- modulate: K[t]/2048 * e^{-2pi i t/4096} ----
    for (int t = t7; t < LSEQ; t += 128) {
        float kv = sb[PAD(t)].x * (1.0f / (float)LSEQ);
        float sn, cs;
        __sincosf(-TWO_PI * (float)t / (float)NF, &sn, &cs);
        sb[PAD(t)] = make_float2(kv * cs, kv * sn);
    }
    __syncthreads();
    // ---- forward DIF 2048 (natural -> dr11-permuted spectrum) ----
    pass16<false>(sb, t7, 128, -TWO_PI * (float)t7 / 2048.f);
    __syncthreads();
    pass16<false>(sb, ((t7 >> 3) << 7) | (t7 & 7), 8,
                  -TWO_PI * (float)(t7 & 7) / 128.f);
    __syncthreads();
    pass8<false>(sb, t7 << 3, 1, 0.f);
    pass8<false>(sb, (t7 + 128) << 3, 1, 0.f);
    __syncthreads();
    const float dD = Dp[hh];
    const float s4 = 1.0f / (float)NF;
    float2* Kh = KfP + (size_t)hh * NF;
    for (int p = t7; p < LSEQ; p += 128) {
        int m = (p & 7) * 256 + ((p >> 3) & 15) * 16 + (p >> 7);  // inv dr11
        int k = 2 * m + 1;
        float2 v = sb[PAD(p)];
        Kh[((k&15)<<8) | (k&240) | (k>>8)] =
            make_float2((v.x + dD) * s4, v.y * s4);
    }
}

// FFT convolution per (b, head-pair): pack 2 real rows as complex, forward
// DIF-4096 (spectrum stays dr12-permuted), Hermitian split+multiply with
// permuted Kf, inverse DIT-4096, store. +D*u and 1/4096 folded into Kf.
__global__ __launch_bounds__(NTH, 4) void k_conv(
    const float2* __restrict__ u2, const float2* __restrict__ Kf,
    float2* __restrict__ out2)
{
    __shared__ float2 s[4352];
    const int idx = blockIdx.x;
    const int x = idx & 7, m = idx >> 3;
    const int b = m >> 5;
    const int hp = x * 32 + (m & 31);   // XCD swizzle: adjacent hp same XCD
    const int tid = threadIdx.x;
    const float2* ub = u2 + (size_t)b * LSEQ * NPAIR + hp;
    for (int t = tid; t < LSEQ; t += NTH) s[PAD(t)] = ub[(size_t)t * NPAIR];
    for (int t = LSEQ + tid; t < NF; t += NTH) s[PAD(t)] = make_float2(0.f, 0.f);
    __syncthreads();
    // forward DIF 4096 = 16*16*16
    pass16<false>(s, tid, 256, -TWO_PI * (float)tid / 4096.f);
    __syncthreads();
    pass16<false>(s, ((tid >> 4) << 8) | (tid & 15), 16,
                  -TWO_PI * (float)(tid & 15) / 256.f);
    __syncthreads();
    pass16<false>(s, tid << 4, 1, 0.f);
    __syncthreads();
    // pointwise in permuted domain
    const float2* K0 = Kf + (size_t)(2 * hp) * NF;
    const float2* K1 = K0 + NF;
    #pragma unroll
    for (int p = tid; p < NF; p += NTH) {
        int k  = ((p & 15) << 8) | (p & 240) | (p >> 8);       // bin at pos p
        int kc = (NF - k) & (NF - 1);
        int pp = ((kc & 15) << 8) | (kc & 240) | (kc >> 8);    // conj bin pos
        if (p > pp) continue;
        if (p == pp) {   // self-conjugate bins (k = 0, 2048): Kf real
            float2 X = s[PAD(p)];
            float2 g0 = K0[p], g1 = K1[p];
            s[PAD(p)] = make_float2(X.x*g0.x - X.y*g1.y, X.x*g0.y + X.y*g1.x);
        } else {
            float2 Xa = s[PAD(p)], Xb = s[PAD(pp)];
            float2 U0 = make_float2(0.5f*(Xa.x + Xb.x), 0.5f*(Xa.y - Xb.y));
            float2 df = make_float2(Xa.x - Xb.x, Xa.y + Xb.y);
            float2 U1 = make_float2(0.5f*df.y, -0.5f*df.x);
            float2 A0 = K0[p], A1 = K1[p], B0 = K0[pp], B1 = K1[pp];
            float2 y0 = cmul(U0, A0), y1 = cmul(U1, A1);
            s[PAD(p)] = make_float2(y0.x - y1.y, y0.y + y1.x);
            float2 U0c = make_float2(U0.x, -U0.y);
            float2 U1c = make_float2(U1.x, -U1.y);
            float2 z0 = cmul(U0c, B0), z1 = cmul(U1c, B1);
            s[PAD(pp)] = make_float2(z0.x - z1.y, z0.y + z1.x);
        }
    }
    __syncthreads();
    // inverse DIT 4096
    pass16<true>(s, tid << 4, 1, 0.f);
    __syncthreads();
    pass16<true>(s, ((tid >> 4) << 8) | (tid & 15), 16,
                 TWO_PI * (float)(tid & 15) / 256.f);
    __syncthreads();
    pass16<true>(s, tid, 256, TWO_PI * (float)tid / 4096.f);
    __syncthreads();
    float2* ob = out2 + (size_t)b * LSEQ * NPAIR + hp;
    for (int t = tid; t < LSEQ; t += NTH) ob[(size_t)t * NPAIR] = s[PAD(t)];
}

extern "C" void kernel_launch(void* const* d_in, const int* in_sizes, int n_in,
                              void* d_out, int out_size, void* d_ws, size_t ws_size,
                              hipStream_t stream) {
    const float* u   = (const float*)d_in[0];
    const float* Lre = (const float*)d_in[1];
    const float* Lim = (const float*)d_in[2];
    const float* P   = (const float*)d_in[3];
    const float* B   = (const float*)d_in[4];
    const float* C   = (const float*)d_in[5];
    const float* D   = (const float*)d_in[6];
    const float* ls  = (const float*)d_in[7];

    float2* KfP   = (float2*)d_ws;        // 16 MB: permuted kernel spectrum
    float2* Aperm = (float2*)d_out;       // 8 MB scratch, overwritten by k_conv

    k_cauchy<<<NH * 2,  NTH, 0, stream>>>(Lre, Lim, P, B, C, D, ls, Aperm, KfP);
    k_kspec <<<NH / 2,  NTH, 0, stream>>>(Aperm, D, KfP);
    k_conv  <<<NB * NPAIR, NTH, 0, stream>>>((const float2*)u, KfP,
                                             (float2*)d_out);
}

// Round 4
// 252.110 us; speedup vs baseline: 3.4571x; 3.4571x over previous
//
#include <hip/hip_runtime.h>
#include <math.h>

#define NTH 256
#define LSEQ 2048
#define NF 4096
#define NH 512
#define NS 64
#define NB 8
#define NPAIR 256
#define TWO_PI 6.2831853071795864769f
#define PAD(i) ((i) + ((i) >> 4))

__device__ __forceinline__ float2 cmul(float2 a, float2 b) {
    return make_float2(a.x*b.x - a.y*b.y, a.x*b.y + a.y*b.x);
}
__device__ __forceinline__ float2 cmulw(float2 a, float wr, float wi) {
    return make_float2(a.x*wr - a.y*wi, a.x*wi + a.y*wr);
}

// ---- 16-point DIF DFT in registers. Output: Y[k] = y[rev4[k]]. ----
template<bool INV>
__device__ __forceinline__ void fft16(float2* y) {
    const float sg = INV ? -1.f : 1.f;
    const float WR[8] = {1.f, 0.9238795325112867f, 0.7071067811865476f,
                         0.3826834323650898f, 0.f, -0.3826834323650898f,
                         -0.7071067811865476f, -0.9238795325112867f};
    const float WI[8] = {0.f, -0.3826834323650898f, -0.7071067811865476f,
                         -0.9238795325112867f, -1.f, -0.9238795325112867f,
                         -0.7071067811865476f, -0.3826834323650898f};
    #pragma unroll
    for (int j = 0; j < 8; ++j) {
        float2 a = y[j], b = y[j+8];
        float2 d = make_float2(a.x-b.x, a.y-b.y);
        y[j] = make_float2(a.x+b.x, a.y+b.y);
        y[j+8] = cmulw(d, WR[j], sg*WI[j]);
    }
    #pragma unroll
    for (int h = 0; h < 16; h += 8)
        #pragma unroll
        for (int j = 0; j < 4; ++j) {
            float2 a = y[h+j], b = y[h+j+4];
            float2 d = make_float2(a.x-b.x, a.y-b.y);
            y[h+j] = make_float2(a.x+b.x, a.y+b.y);
            y[h+j+4] = cmulw(d, WR[2*j], sg*WI[2*j]);
        }
    #pragma unroll
    for (int h = 0; h < 16; h += 4)
        #pragma unroll
        for (int j = 0; j < 2; ++j) {
            float2 a = y[h+j], b = y[h+j+2];
            float2 d = make_float2(a.x-b.x, a.y-b.y);
            y[h+j] = make_float2(a.x+b.x, a.y+b.y);
            y[h+j+2] = (j == 0) ? d : make_float2(sg*d.y, -sg*d.x);
        }
    #pragma unroll
    for (int h = 0; h < 16; h += 2) {
        float2 a = y[h], b = y[h+1];
        y[h] = make_float2(a.x+b.x, a.y+b.y);
        y[h+1] = make_float2(a.x-b.x, a.y-b.y);
    }
}

// ---- 8-point DIF DFT in registers. Output: Y[k] = y[rev3[k]]. ----
template<bool INV>
__device__ __forceinline__ void fft8(float2* y) {
    const float sg = INV ? -1.f : 1.f;
    const float RH = 0.7071067811865476f;
    const float WR[4] = {1.f, RH, 0.f, -RH};
    const float WI[4] = {0.f, -RH, -1.f, -RH};
    #pragma unroll
    for (int j = 0; j < 4; ++j) {
        float2 a = y[j], b = y[j+4];
        float2 d = make_float2(a.x-b.x, a.y-b.y);
        y[j] = make_float2(a.x+b.x, a.y+b.y);
        y[j+4] = cmulw(d, WR[j], sg*WI[j]);
    }
    #pragma unroll
    for (int h = 0; h < 8; h += 4)
        #pragma unroll
        for (int j = 0; j < 2; ++j) {
            float2 a = y[h+j], b = y[h+j+2];
            float2 d = make_float2(a.x-b.x, a.y-b.y);
            y[h+j] = make_float2(a.x+b.x, a.y+b.y);
            y[h+j+2] = (j == 0) ? d : make_float2(sg*d.y, -sg*d.x);
        }
    #pragma unroll
    for (int h = 0; h < 8; h += 2) {
        float2 a = y[h], b = y[h+1];
        y[h] = make_float2(a.x+b.x, a.y+b.y);
        y[h+1] = make_float2(a.x-b.x, a.y-b.y);
    }
}

// Radix-16 pass on padded LDS. INV=false: DIF forward (natural->DR order).
// INV=true: DIT inverse (DR->natural).
template<bool INV>
__device__ __forceinline__ void pass16(float2* s, int base, int str, float ang1) {
    const int rev4[16] = {0,8,4,12,2,10,6,14,1,9,5,13,3,11,7,15};
    float2 y[16];
    float sn, cs;
    __sincosf(ang1, &sn, &cs);
    float2 wb = make_float2(cs, sn);
    if (!INV) {
        #pragma unroll
        for (int j = 0; j < 16; ++j) y[j] = s[PAD(base + j*str)];
        fft16<false>(y);
        float2 w = make_float2(1.f, 0.f);
        s[PAD(base)] = y[0];
        #pragma unroll
        for (int k = 1; k < 16; ++k) {
            w = cmul(w, wb);
            s[PAD(base + k*str)] = cmul(y[rev4[k]], w);
        }
    } else {
        float2 w = make_float2(1.f, 0.f);
        y[0] = s[PAD(base)];
        #pragma unroll
        for (int k = 1; k < 16; ++k) {
            w = cmul(w, wb);
            y[k] = cmul(s[PAD(base + k*str)], w);
        }
        fft16<true>(y);
        #pragma unroll
        for (int j = 0; j < 16; ++j) s[PAD(base + j*str)] = y[rev4[j]];
    }
}

template<bool INV>
__device__ __forceinline__ void pass8(float2* s, int base, int str, float ang1) {
    const int rev3[8] = {0,4,2,6,1,5,3,7};
    float2 y[8];
    float sn, cs;
    __sincosf(ang1, &sn, &cs);
    float2 wb = make_float2(cs, sn);
    if (!INV) {
        #pragma unroll
        for (int j = 0; j < 8; ++j) y[j] = s[PAD(base + j*str)];
        fft8<false>(y);
        float2 w = make_float2(1.f, 0.f);
        s[PAD(base)] = y[0];
        #pragma unroll
        for (int k = 1; k < 8; ++k) {
            w = cmul(w, wb);
            s[PAD(base + k*str)] = cmul(y[rev3[k]], w);
        }
    } else {
        float2 w = make_float2(1.f, 0.f);
        y[0] = s[PAD(base)];
        #pragma unroll
        for (int k = 1; k < 8; ++k) {
            w = cmul(w, wb);
            y[k] = cmul(s[PAD(base + k*str)], w);
        }
        fft8<true>(y);
        #pragma unroll
        for (int j = 0; j < 8; ++j) s[PAD(base + j*str)] = y[rev3[j]];
    }
}

__device__ __forceinline__ float2 finalize_ar(const float* s, float tg) {
    float denx = 1.0f + s[6], deny = s[7];
    float dinv = 1.0f / (denx*denx + deny*deny);
    float numx = s[2]*s[4] - s[3]*s[5];
    float numy = s[2]*s[5] + s[3]*s[4];
    float qx = (numx*denx + numy*deny) * dinv;
    float qy = (numy*denx - numx*deny) * dinv;
    float kx = s[0] - qx, ky = s[1] - qy;
    return make_float2(kx - tg*ky, ky + tg*kx);   // (1 + i*tg) * k
}

// Merged kernel-generator: one block per head.
// Cauchy (coeffs in LDS, no register blowup) -> A in sA (natural) and sW
// (dr11-scattered) -> IDIT-2048 -> modulate -> DIF-2048 -> single coalesced
// store of all 4096 Kf bins (dr12-permuted layout), gathering from LDS.
__global__ __launch_bounds__(NTH) void k_kern(
    const float* __restrict__ Lre, const float* __restrict__ Lim,
    const float* __restrict__ Pm, const float* __restrict__ Bm,
    const float* __restrict__ Cm, const float* __restrict__ Dp,
    const float* __restrict__ logstep, float2* __restrict__ KfP)
{
    __shared__ float2 sA[LSEQ];          // A, natural order (preserved)
    __shared__ float2 sW[2176];          // padded FFT working array
    __shared__ float2 lamS[NS], c00S[NS], c01S[NS], c10S[NS];
    __shared__ float c11S[NS];
    __shared__ float2 S00tot;
    const int h = blockIdx.x;
    const int tid = threadIdx.x;
    if (tid < NS) {
        int i = h * NS + tid;
        float Lx = fminf(Lre[i], -1e-4f), Ly = Lim[i];
        float Px = Pm[2*i], Py = Pm[2*i+1];
        float Bx = Bm[2*i], By = Bm[2*i+1];
        float Cx = Cm[2*i], Cy = Cm[2*i+1];
        lamS[tid] = make_float2(Lx, Ly);
        c00S[tid] = make_float2(Cx*Bx + Cy*By, Cx*By - Cy*Bx);  // conj(C)*B
        c01S[tid] = make_float2(Cx*Px + Cy*Py, Cx*Py - Cy*Px);  // conj(C)*P
        c10S[tid] = make_float2(Px*Bx + Py*By, Px*By - Py*Bx);  // conj(P)*B
        c11S[tid] = Px*Px + Py*Py;                              // conj(P)*P
    }
    __syncthreads();
    if (tid == 0) {
        float2 acc = make_float2(0.f, 0.f);
        for (int n = 0; n < NS; ++n) { acc.x += c00S[n].x; acc.y += c00S[n].y; }
        S00tot = acc;
    }
    __syncthreads();
    const float step = expf(logstep[h]);
    const float a2s = 2.0f / step;
    for (int l = tid; l <= LSEQ/2; l += NTH) {
        const int lp = LSEQ - l;
        float2 ar1, ar2;
        if (l == LSEQ/2) {  // tan -> inf: c_scale*k -> (step/2)*sum(c00)
            ar1 = make_float2(0.5f*step*S00tot.x, 0.5f*step*S00tot.y);
            ar2 = ar1;
        } else {
            float r1 = (float)l  * (1.0f / (float)LSEQ);
            float r2 = (float)lp * (1.0f / (float)LSEQ);
            float tg1 = sinpif(r1) / cospif(r1);
            float tg2 = sinpif(r2) / cospif(r2);
            float g1 = a2s * tg1, g2 = a2s * tg2;
            float sa[8] = {0,0,0,0,0,0,0,0};
            float sb[8] = {0,0,0,0,0,0,0,0};
            #pragma unroll 4
            for (int n = 0; n < NS; ++n) {
                float2 lam = lamS[n];
                float2 a0 = c00S[n], a1 = c01S[n], a2 = c10S[n];
                float a3x = c11S[n];
                float dre = -lam.x;
                float di1 = g1 - lam.y, di2 = g2 - lam.y;
                float iv1 = 1.0f / (dre*dre + di1*di1);
                float iv2 = 1.0f / (dre*dre + di2*di2);
                float rx1 = dre*iv1, ry1 = -di1*iv1;
                float rx2 = dre*iv2, ry2 = -di2*iv2;
                sa[0] += a0.x*rx1 - a0.y*ry1; sa[1] += a0.x*ry1 + a0.y*rx1;
                sa[2] += a1.x*rx1 - a1.y*ry1; sa[3] += a1.x*ry1 + a1.y*rx1;
                sa[4] += a2.x*rx1 - a2.y*ry1; sa[5] += a2.x*ry1 + a2.y*rx1;
                sa[6] += a3x*rx1;             sa[7] += a3x*ry1;
                sb[0] += a0.x*rx2 - a0.y*ry2; sb[1] += a0.x*ry2 + a0.y*rx2;
                sb[2] += a1.x*rx2 - a1.y*ry2; sb[3] += a1.x*ry2 + a1.y*rx2;
                sb[4] += a2.x*rx2 - a2.y*ry2; sb[5] += a2.x*ry2 + a2.y*rx2;
                sb[6] += a3x*rx2;             sb[7] += a3x*ry2;
            }
            float tgq1 = (l == 0) ? 0.f : sinpif((float)l * (1.0f/(float)LSEQ))
                                        / cospif((float)l * (1.0f/(float)LSEQ));
            (void)tgq1;
            ar1 = finalize_ar(sa, tg1);
            ar2 = finalize_ar(sb, tg2);
        }
        // A[l] = (at[l] + conj(at[2048-l]))/2 ; A[2048-l] = conj(A[l])
        float2 A = make_float2(0.5f*(ar1.x + ar2.x), 0.5f*(ar1.y - ar2.y));
        const int l2 = lp & (LSEQ - 1);
        sA[l] = A;
        sW[PAD(((l&15)<<7) | (((l>>4)&15)<<3) | (l>>8))] = A;
        if (l2 != l) {
            float2 Ac = make_float2(A.x, -A.y);
            sA[l2] = Ac;
            sW[PAD(((l2&15)<<7) | (((l2>>4)&15)<<3) | (l2>>8))] = Ac;
        }
    }
    __syncthreads();
    // ---- inverse DIT-2048 on sW (DR input -> natural time) ----
    pass8<true>(sW, tid << 3, 1, 0.f);
    __syncthreads();
    if (tid < 128) pass16<true>(sW, ((tid >> 3) << 7) | (tid & 7), 8,
                                TWO_PI * (float)(tid & 7) / 128.f);
    __syncthreads();
    if (tid < 128) pass16<true>(sW, tid, 128, TWO_PI * (float)tid / 2048.f);
    __syncthreads();
    // ---- modulate: K[t]/2048 * e^{-2pi i t/4096} ----
    for (int t = tid; t < LSEQ; t += NTH) {
        float kv = sW[PAD(t)].x * (1.0f / (float)LSEQ);
        float sn, cs;
        __sincosf(-TWO_PI * (float)t / (float)NF, &sn, &cs);
        sW[PAD(t)] = make_float2(kv * cs, kv * sn);
    }
    __syncthreads();
    // ---- forward DIF-2048 (natural -> DR spectrum) ----
    if (tid < 128) pass16<false>(sW, tid, 128, -TWO_PI * (float)tid / 2048.f);
    __syncthreads();
    if (tid < 128) pass16<false>(sW, ((tid >> 3) << 7) | (tid & 7), 8,
                                 -TWO_PI * (float)(tid & 7) / 128.f);
    __syncthreads();
    pass8<false>(sW, tid << 3, 1, 0.f);
    __syncthreads();
    // ---- single coalesced store of all bins in dr12-permuted layout ----
    const float dD = Dp[h];
    const float s4 = 1.0f / (float)NF;
    float2* Kh = KfP + (size_t)h * NF;
    #pragma unroll
    for (int j = 0; j < NF / NTH; ++j) {
        int p = j * NTH + tid;
        int k = ((p & 15) << 8) | (p & 240) | (p >> 8);   // bin at position p
        float2 v;
        if (k & 1) {   // odd bin: from modulated spectrum (dr11 order in sW)
            int m = k >> 1;
            v = sW[PAD(((m&15)<<7) | (((m>>4)&15)<<3) | (m>>8))];
        } else {       // even bin: A[k/2] directly
            v = sA[k >> 1];
        }
        Kh[p] = make_float2((v.x + dD) * s4, v.y * s4);
    }
}

// FFT convolution per (b, head-pair): pack 2 real rows as complex, forward
// DIF-4096 (spectrum stays dr12-permuted), Hermitian split+multiply with
// permuted Kf, inverse DIT-4096, store. +D*u and 1/4096 folded into Kf.
__global__ __launch_bounds__(NTH, 4) void k_conv(
    const float2* __restrict__ u2, const float2* __restrict__ Kf,
    float2* __restrict__ out2)
{
    __shared__ float2 s[4352];
    const int idx = blockIdx.x;
    const int x = idx & 7, m = idx >> 3;
    const int b = m >> 5;
    const int hp = x * 32 + (m & 31);   // XCD swizzle: adjacent hp same XCD
    const int tid = threadIdx.x;
    const float2* ub = u2 + (size_t)b * LSEQ * NPAIR + hp;
    for (int t = tid; t < LSEQ; t += NTH) s[PAD(t)] = ub[(size_t)t * NPAIR];
    for (int t = LSEQ + tid; t < NF; t += NTH) s[PAD(t)] = make_float2(0.f, 0.f);
    __syncthreads();
    // forward DIF 4096 = 16*16*16
    pass16<false>(s, tid, 256, -TWO_PI * (float)tid / 4096.f);
    __syncthreads();
    pass16<false>(s, ((tid >> 4) << 8) | (tid & 15), 16,
                  -TWO_PI * (float)(tid & 15) / 256.f);
    __syncthreads();
    pass16<false>(s, tid << 4, 1, 0.f);
    __syncthreads();
    // pointwise in permuted domain
    const float2* K0 = Kf + (size_t)(2 * hp) * NF;
    const float2* K1 = K0 + NF;
    for (int p = tid; p < NF; p += NTH) {
        int k  = ((p & 15) << 8) | (p & 240) | (p >> 8);       // bin at pos p
        int kc = (NF - k) & (NF - 1);
        int pp = ((kc & 15) << 8) | (kc & 240) | (kc >> 8);    // conj bin pos
        if (p > pp) continue;
        if (p == pp) {   // self-conjugate bins (k = 0, 2048)
            float2 X = s[PAD(p)];
            float2 g0 = K0[p], g1 = K1[p];
            s[PAD(p)] = make_float2(X.x*g0.x - X.y*g1.y, X.x*g0.y + X.y*g1.x);
        } else {
            float2 Xa = s[PAD(p)], Xb = s[PAD(pp)];
            float2 U0 = make_float2(0.5f*(Xa.x + Xb.x), 0.5f*(Xa.y - Xb.y));
            float2 df = make_float2(Xa.x - Xb.x, Xa.y + Xb.y);
            float2 U1 = make_float2(0.5f*df.y, -0.5f*df.x);
            float2 A0 = K0[p], A1 = K1[p], B0 = K0[pp], B1 = K1[pp];
            float2 y0 = cmul(U0, A0), y1 = cmul(U1, A1);
            s[PAD(p)] = make_float2(y0.x - y1.y, y0.y + y1.x);
            float2 U0c = make_float2(U0.x, -U0.y);
            float2 U1c = make_float2(U1.x, -U1.y);
            float2 z0 = cmul(U0c, B0), z1 = cmul(U1c, B1);
            s[PAD(pp)] = make_float2(z0.x - z1.y, z0.y + z1.x);
        }
    }
    __syncthreads();
    // inverse DIT 4096
    pass16<true>(s, tid << 4, 1, 0.f);
    __syncthreads();
    pass16<true>(s, ((tid >> 4) << 8) | (tid & 15), 16,
                 TWO_PI * (float)(tid & 15) / 256.f);
    __syncthreads();
    pass16<true>(s, tid, 256, TWO_PI * (float)tid / 4096.f);
    __syncthreads();
    float2* ob = out2 + (size_t)b * LSEQ * NPAIR + hp;
    for (int t = tid; t < LSEQ; t += NTH) ob[(size_t)t * NPAIR] = s[PAD(t)];
}

extern "C" void kernel_launch(void* const* d_in, const int* in_sizes, int n_in,
                              void* d_out, int out_size, void* d_ws, size_t ws_size,
                              hipStream_t stream) {
    const float* u   = (const float*)d_in[0];
    const float* Lre = (const float*)d_in[1];
    const float* Lim = (const float*)d_in[2];
    const float* P   = (const float*)d_in[3];
    const float* B   = (const float*)d_in[4];
    const float* C   = (const float*)d_in[5];
    const float* D   = (const float*)d_in[6];
    const float* ls  = (const float*)d_in[7];

    float2* KfP = (float2*)d_ws;          // 16 MB: permuted kernel spectrum

    k_kern<<<NH, NTH, 0, stream>>>(Lre, Lim, P, B, C, D, ls, KfP);
    k_conv<<<NB * NPAIR, NTH, 0, stream>>>((const float2*)u, KfP,
                                           (float2*)d_out);
}